// Round 7
// baseline (150.147 us; speedup 1.0000x reference)
//
#include <hip/hip_runtime.h>

// Batched GEMM: C[b][i][j] = sum_d A[b][i][d] * B[b][j][d]
// B=16, M=N=1024, K=256, fp32 in/out, bf16 MFMA compute.
// R7: NO LDS, NO barriers. MFMA fragments loaded directly from global
//     (row-major K-contig matches the 16x16x32 A/B lane layout: lanes
//     {r,r+16,r+32,r+48} cover 128B of row r contiguously = perfect 64B-line
//     utilization). fp32->bf16 convert in-register. Waves fully independent;
//     K-step prefetch (loads k+1 issued before MFMA k). NT stores for C.

typedef __attribute__((ext_vector_type(8))) short bf16x8;
typedef __attribute__((ext_vector_type(4))) float f32x4;
typedef __attribute__((ext_vector_type(4))) unsigned int u32x4;

#define NBATCH 16
#define MDIM 1024
#define NDIM 1024
#define KDIM 256

// round-half-up fp32->bf16 pair pack: lo16 = bf(f0), hi16 = bf(f1)
__device__ __forceinline__ unsigned pack_bf2(float f0, float f1) {
  unsigned u0 = __builtin_bit_cast(unsigned, f0) + 0x8000u;
  unsigned u1 = __builtin_bit_cast(unsigned, f1) + 0x8000u;
  return __builtin_amdgcn_perm(u1, u0, 0x07060302u);
}

__global__ __launch_bounds__(256, 2) void batched_gemm_bt(
    const float* __restrict__ A, const float* __restrict__ B,
    float* __restrict__ C) {
  // XCD chunk swizzle: hardware XCD = bid%8; remap so XCD x runs blocks
  // [x*128,(x+1)*128) = batches {2x,2x+1} -> input working set = its L2.
  const int bid = blockIdx.x;
  const int nb  = ((bid & 7) << 7) | (bid >> 3);
  const int batch = nb >> 6;  // 64 tiles (8x8) per batch
  const int tile  = nb & 63;
  const int tm = tile >> 3, tn = tile & 7;

  const int tid  = threadIdx.x;
  const int lane = tid & 63;
  const int wid  = tid >> 6;
  const int wr = wid >> 1, wc = wid & 1;  // wave 2x2 grid, each 64x64 out

  const int lrow = lane & 15;  // fragment row
  const int hi   = lane >> 4;  // k-subslice: floats [hi*8, hi*8+8) of each 32-float step

  // Per-lane fragment base pointers (frag m adds m*16 rows).
  const float* a0 = A + ((size_t)batch * MDIM + tm * 128 + wr * 64 + lrow) * KDIM + hi * 8;
  const float* b0 = B + ((size_t)batch * NDIM + tn * 128 + wc * 64 + lrow) * KDIM + hi * 8;

  f32x4 sa[4][2], sb[4][2];   // fp32 staging: [frag][half-16B]
  u32x4 af[4], bf[4];         // converted bf16 fragments (8 bf16 each)
  f32x4 acc[4][4];
#pragma unroll
  for (int m = 0; m < 4; ++m)
#pragma unroll
    for (int n = 0; n < 4; ++n)
      acc[m][n] = (f32x4){0.f, 0.f, 0.f, 0.f};

#define LOADS(kt)                                                         \
  do {                                                                    \
    _Pragma("unroll") for (int m = 0; m < 4; ++m) {                       \
      sa[m][0] = *(const f32x4*)(a0 + (size_t)m * 16 * KDIM + (kt) * 32); \
      sa[m][1] = *(const f32x4*)(a0 + (size_t)m * 16 * KDIM + (kt) * 32 + 4); \
      sb[m][0] = *(const f32x4*)(b0 + (size_t)m * 16 * KDIM + (kt) * 32); \
      sb[m][1] = *(const f32x4*)(b0 + (size_t)m * 16 * KDIM + (kt) * 32 + 4); \
    }                                                                     \
  } while (0)

#define CONVERT()                                                         \
  do {                                                                    \
    _Pragma("unroll") for (int m = 0; m < 4; ++m) {                       \
      af[m][0] = pack_bf2(sa[m][0][0], sa[m][0][1]);                      \
      af[m][1] = pack_bf2(sa[m][0][2], sa[m][0][3]);                      \
      af[m][2] = pack_bf2(sa[m][1][0], sa[m][1][1]);                      \
      af[m][3] = pack_bf2(sa[m][1][2], sa[m][1][3]);                      \
      bf[m][0] = pack_bf2(sb[m][0][0], sb[m][0][1]);                      \
      bf[m][1] = pack_bf2(sb[m][0][2], sb[m][0][3]);                      \
      bf[m][2] = pack_bf2(sb[m][1][0], sb[m][1][1]);                      \
      bf[m][3] = pack_bf2(sb[m][1][2], sb[m][1][3]);                      \
    }                                                                     \
  } while (0)

#define MFMAS()                                                           \
  do {                                                                    \
    _Pragma("unroll") for (int m = 0; m < 4; ++m)                         \
      _Pragma("unroll") for (int n = 0; n < 4; ++n)                       \
        acc[m][n] = __builtin_amdgcn_mfma_f32_16x16x32_bf16(              \
            __builtin_bit_cast(bf16x8, af[m]),                            \
            __builtin_bit_cast(bf16x8, bf[n]), acc[m][n], 0, 0, 0);       \
  } while (0)

  // K = 256 -> 8 steps of 32. Convert(k) consumes loads issued last iter
  // (in flight across ~32 MFMA + 96 VALU ~= L2 latency); loads(k+1) issued
  // before the MFMA block. No barriers anywhere.
  LOADS(0);
#pragma unroll
  for (int kt = 0; kt < 8; ++kt) {
    CONVERT();
    if (kt < 7) LOADS(kt + 1);
    MFMAS();
  }

#undef LOADS
#undef CONVERT
#undef MFMAS

  // C/D layout: col = lane&15, row = (lane>>4)*4 + reg (m89-verified).
  // NT stores: C lines never re-read -> don't evict input panels from L2.
  float* Cb = C + (size_t)batch * MDIM * NDIM + (size_t)(tm * 128) * NDIM + tn * 128;
  float* cw = Cb + (size_t)(wr * 64 + hi * 4) * NDIM + wc * 64 + lrow;
#pragma unroll
  for (int m = 0; m < 4; ++m)
#pragma unroll
    for (int n = 0; n < 4; ++n)
#pragma unroll
      for (int j = 0; j < 4; ++j)
        __builtin_nontemporal_store(acc[m][n][j],
                                    &cw[(size_t)(m * 16 + j) * NDIM + n * 16]);
}

extern "C" void kernel_launch(void* const* d_in, const int* in_sizes, int n_in,
                              void* d_out, int out_size, void* d_ws, size_t ws_size,
                              hipStream_t stream) {
  const float* A = (const float*)d_in[0];
  const float* B = (const float*)d_in[1];
  float* C = (float*)d_out;
  batched_gemm_bt<<<dim3(NBATCH * 8 * 8), dim3(256), 0, stream>>>(A, B, C);
}

// Round 8
// 105.463 us; speedup vs baseline: 1.4237x; 1.4237x over previous
//
#include <hip/hip_runtime.h>

// Batched GEMM: C[b][i][j] = sum_d A[b][i][d] * B[b][j][d]
// B=16, M=N=1024, K=256, fp32 in/out, bf16 MFMA compute.
// R8: T3-minimum 2-phase with global_load_lds DMA staging of fp32 (async,
//     no VGPR round-trip -> compiler can't serialize it like R7). fp32->bf16
//     convert at LDS-read time. Source-side XOR swizzle (rule #21) makes
//     ds_read_b128 uniform 8-lanes/16B-column = b128 optimum. NT stores.

typedef __attribute__((ext_vector_type(8))) short bf16x8;
typedef __attribute__((ext_vector_type(4))) float f32x4;
typedef __attribute__((ext_vector_type(4))) unsigned int u32x4;

#define NBATCH 16
#define MDIM 1024
#define NDIM 1024
#define KDIM 256
#define BK 32

// round-half-up fp32->bf16 pair pack: lo16 = bf(f0), hi16 = bf(f1)
__device__ __forceinline__ unsigned pack_bf2(float f0, float f1) {
  unsigned u0 = __builtin_bit_cast(unsigned, f0) + 0x8000u;
  unsigned u1 = __builtin_bit_cast(unsigned, f1) + 0x8000u;
  return __builtin_amdgcn_perm(u1, u0, 0x07060302u);
}

__global__ __launch_bounds__(256, 2) void batched_gemm_bt(
    const float* __restrict__ A, const float* __restrict__ B,
    float* __restrict__ C) {
  // XCD chunk swizzle: each XCD works a contiguous 128-block chunk
  // (= 2 batches -> 4MB input working set = its L2).
  const int bid = blockIdx.x;
  const int nb  = ((bid & 7) << 7) | (bid >> 3);
  const int batch = nb >> 6;  // 64 tiles (8x8) per batch
  const int tile  = nb & 63;
  const int tm = tile >> 3, tn = tile & 7;

  const float* Ab = A + ((size_t)batch * MDIM + tm * 128) * KDIM;
  const float* Bb = B + ((size_t)batch * NDIM + tn * 128) * KDIM;

  // fp32 tiles: [buf][A/B][row*32 + col], 128 rows x 32 k-floats = 16KB each.
  // Total 2*2*16KB = 64 KiB -> 2 blocks/CU.
  __shared__ float lds[2][2][128 * BK];

  const int tid  = threadIdx.x;
  const int lane = tid & 63;
  const int wid  = tid >> 6;
  const int wr = wid >> 1, wc = wid & 1;  // wave 2x2 grid, each 64x64 out

  // ---- DMA staging: instr (wid,i) fills LDS rows (wid*4+i)*8 .. +7 ----
  // dest linear: base + lane*16B -> row = block*8 + (lane>>3), col16 = lane&7.
  // source pre-swizzled: col16_src = (lane&7) ^ (lane>>3)  (row&7 == lane>>3).
  const int l8  = lane >> 3;
  const int c16 = (lane & 7) ^ l8;
  const float* asrc = Ab + ((size_t)(wid * 4) * 8 + l8) * KDIM + c16 * 4;
  const float* bsrc = Bb + ((size_t)(wid * 4) * 8 + l8) * KDIM + c16 * 4;

  // ---- fragment read params: lane -> row lrow (+m*16), k-floats [hi*8,+8) ----
  const int hi   = lane >> 4;
  const int lrow = lane & 15;
  const int l7   = lrow & 7;

  f32x4 acc[4][4];
#pragma unroll
  for (int m = 0; m < 4; ++m)
#pragma unroll
    for (int n = 0; n < 4; ++n)
      acc[m][n] = (f32x4){0.f, 0.f, 0.f, 0.f};

#define STAGE(kt, q)                                                          \
  do {                                                                        \
    _Pragma("unroll") for (int i = 0; i < 4; ++i) {                           \
      __builtin_amdgcn_global_load_lds(                                       \
          (const __attribute__((address_space(1))) void*)(asrc + (kt) * 32 +  \
                                                          i * 8 * KDIM),      \
          (__attribute__((address_space(3))) void*)&lds[q][0][(wid * 4 + i) * \
                                                              256],           \
          16, 0, 0);                                                          \
      __builtin_amdgcn_global_load_lds(                                       \
          (const __attribute__((address_space(1))) void*)(bsrc + (kt) * 32 +  \
                                                          i * 8 * KDIM),      \
          (__attribute__((address_space(3))) void*)&lds[q][1][(wid * 4 + i) * \
                                                              256],           \
          16, 0, 0);                                                          \
    }                                                                         \
  } while (0)

  // read fragment row, unswizzle (same XOR as source), pack to bf16, MFMA
#define COMPUTE(q)                                                            \
  do {                                                                        \
    const float* la = &lds[q][0][0];                                          \
    const float* lb = &lds[q][1][0];                                          \
    u32x4 af[4], bfv[4];                                                      \
    _Pragma("unroll") for (int m = 0; m < 4; ++m) {                           \
      const float* pr = la + (wr * 64 + m * 16 + lrow) * 32;                  \
      f32x4 x0 = *(const f32x4*)(pr + (((2 * hi) ^ l7) * 4));                 \
      f32x4 x1 = *(const f32x4*)(pr + (((2 * hi + 1) ^ l7) * 4));             \
      af[m][0] = pack_bf2(x0[0], x0[1]);                                      \
      af[m][1] = pack_bf2(x0[2], x0[3]);                                      \
      af[m][2] = pack_bf2(x1[0], x1[1]);                                      \
      af[m][3] = pack_bf2(x1[2], x1[3]);                                      \
    }                                                                         \
    _Pragma("unroll") for (int n = 0; n < 4; ++n) {                           \
      const float* pr = lb + (wc * 64 + n * 16 + lrow) * 32;                  \
      f32x4 x0 = *(const f32x4*)(pr + (((2 * hi) ^ l7) * 4));                 \
      f32x4 x1 = *(const f32x4*)(pr + (((2 * hi + 1) ^ l7) * 4));             \
      bfv[n][0] = pack_bf2(x0[0], x0[1]);                                     \
      bfv[n][1] = pack_bf2(x0[2], x0[3]);                                     \
      bfv[n][2] = pack_bf2(x1[0], x1[1]);                                     \
      bfv[n][3] = pack_bf2(x1[2], x1[3]);                                     \
    }                                                                         \
    _Pragma("unroll") for (int m = 0; m < 4; ++m)                             \
      _Pragma("unroll") for (int n = 0; n < 4; ++n)                           \
        acc[m][n] = __builtin_amdgcn_mfma_f32_16x16x32_bf16(                  \
            __builtin_bit_cast(bf16x8, af[m]),                                \
            __builtin_bit_cast(bf16x8, bfv[n]), acc[m][n], 0, 0, 0);          \
  } while (0)

  // K = 256 -> 8 steps of BK=32. STAGE(k+1) issued before COMPUTE(k); the
  // __syncthreads vmcnt(0) drain then finds the DMA ~a full compute-phase
  // into flight. Double-buffered; DMA writes buf (k+1)&1 while reads hit k&1.
  STAGE(0, 0);
  __syncthreads();
#pragma unroll
  for (int k = 0; k < 8; ++k) {
    if (k < 7) STAGE(k + 1, (k + 1) & 1);
    COMPUTE(k & 1);
    __syncthreads();
  }

#undef STAGE
#undef COMPUTE

  // C/D layout: col = lane&15, row = (lane>>4)*4 + reg (m89-verified).
  // NT stores: C never re-read -> don't evict input panels from L2/L3.
  float* Cb = C + (size_t)batch * MDIM * NDIM + (size_t)(tm * 128) * NDIM + tn * 128;
  float* cw = Cb + (size_t)(wr * 64 + hi * 4) * NDIM + wc * 64 + lrow;
#pragma unroll
  for (int m = 0; m < 4; ++m)
#pragma unroll
    for (int n = 0; n < 4; ++n)
#pragma unroll
      for (int j = 0; j < 4; ++j)
        __builtin_nontemporal_store(acc[m][n][j],
                                    &cw[(size_t)(m * 16 + j) * NDIM + n * 16]);
}

extern "C" void kernel_launch(void* const* d_in, const int* in_sizes, int n_in,
                              void* d_out, int out_size, void* d_ws, size_t ws_size,
                              hipStream_t stream) {
  const float* A = (const float*)d_in[0];
  const float* B = (const float*)d_in[1];
  float* C = (float*)d_out;
  batched_gemm_bt<<<dim3(NBATCH * 8 * 8), dim3(256), 0, stream>>>(A, B, C);
}